// Round 9
// baseline (353.323 us; speedup 1.0000x reference)
//
#include <hip/hip_runtime.h>
#include <math.h>

#define BB 4
#define NN 4096
#define KK 16
#define CIN 32
#define BN_INV 0.9999950000375f

#define RS 32    // candidate ranges per query
#define PCH 128  // candidates per range (NN/RS)
#define PK 8     // prefilter top-K per range
#define NG 4     // merge groups (8 ranges each)
#define NK2 24   // candidates fp64-reranked per group

typedef float f32x2 __attribute__((ext_vector_type(2)));

// ---------------- P0: derived W1 weights + padded W3/W4 copies ----------------
__global__ void p0_weights(const float* __restrict__ W1,
                           const float* __restrict__ W3, const float* __restrict__ W4,
                           float* __restrict__ Aw, float* __restrict__ Bw,
                           float* __restrict__ w1d,
                           float* __restrict__ W3p, float* __restrict__ W4p) {
    int t = threadIdx.x;
    for (int i = t; i < 64 * 32; i += 256) {
        int o = i >> 5, c = i & 31;
        Aw[i] = W1[o * 128 + c] - W1[o * 128 + 64 + c];
        Bw[i] = W1[o * 128 + 32 + c] + W1[o * 128 + 64 + c];
    }
    if (t < 64) {
        float s = 0.f;
        for (int c = 96; c < 128; ++c) s += W1[t * 128 + c];
        w1d[t] = s;
    }
    for (int i = t; i < 32 * 14; i += 256) {
        int r = i / 14, j = i - r * 14;
        W3p[i] = (j < 13) ? W3[r * 13 + j] : 0.f;
        W4p[i] = (j < 13) ? W4[r * 13 + j] : 0.f;
    }
}

// ---------------- P1: transpose features to [B,N,32] + fp32/fp64 norms ----------------
__global__ void p1_transpose(const float* __restrict__ f, float* __restrict__ pT,
                             float* __restrict__ sq32, double* __restrict__ sq64) {
    int g = blockIdx.x * 256 + threadIdx.x;  // b*N + n
    int b = g >> 12, n = g & (NN - 1);
    float v[CIN];
#pragma unroll
    for (int c = 0; c < CIN; ++c) v[c] = f[(b * CIN + c) * NN + n];
#pragma unroll
    for (int c = 0; c < CIN; ++c) pT[(size_t)g * CIN + c] = v[c];
    // sequential chain — BITWISE identical to knn_prefilter's per-lane dot chain
    float s32 = 0.f;
#pragma unroll
    for (int c = 0; c < CIN; ++c) s32 = fmaf(v[c], v[c], s32);
    sq32[g] = s32;
    // sequential fp64 chain — must match knn_merge's rerank chains
    double s64 = 0.0;
#pragma unroll
    for (int c = 0; c < CIN; ++c) s64 = fma((double)v[c], (double)v[c], s64);
    sq64[g] = s64;
}

// ---------------- P2: per-point projections ctrA = A*p, nbrB = B*p ----------------
__global__ __launch_bounds__(256) void p2_proj(const float* __restrict__ pT,
                                               const float* __restrict__ Aw,
                                               const float* __restrict__ Bw,
                                               float* __restrict__ ctrA,
                                               float* __restrict__ nbrB) {
    __shared__ float sA[32 * 64], sB[32 * 64];
    for (int i = threadIdx.x; i < 2048; i += 256) {
        int o = i >> 5, c = i & 31;
        sA[c * 64 + o] = Aw[i];
        sB[c * 64 + o] = Bw[i];
    }
    __syncthreads();
    int g = blockIdx.x * 256 + threadIdx.x;  // (b*N+n)*64 + o
    int o = g & 63;
    int pn = g >> 6;
    const float* p = pT + (size_t)pn * 32;
    float a = 0.f, bb = 0.f;
#pragma unroll
    for (int c = 0; c < 32; ++c) {
        float pv = p[c];
        a = fmaf(sA[c * 64 + o], pv, a);
        bb = fmaf(sB[c * 64 + o], pv, bb);
    }
    ctrA[g] = a;
    nbrB[g] = bb;
}

// ---------------- KNN prefilter: 2 queries/thread packed in pk lanes ----------------
__global__ __launch_bounds__(256) void knn_prefilter(const float* __restrict__ pT,
                                                     const float* __restrict__ sq32,
                                                     unsigned* __restrict__ pkey) {
    __shared__ float tile[PCH * 32];   // 16 KB candidate tile
    __shared__ float tsq[PCH];
    int tid = threadIdx.x;
    int qbase = blockIdx.x * 512;
    int n0 = qbase + tid;          // query in lane .x
    int n1 = qbase + 256 + tid;    // query in lane .y
    int b = n0 >> 12;
    const float* pb = pT + ((size_t)(b << 12)) * 32;
    int m0 = blockIdx.y * PCH;

    {
        const float4* src = (const float4*)(pb + (size_t)m0 * 32);
        float4* dst = (float4*)tile;
#pragma unroll
        for (int i = 0; i < 4; ++i) dst[tid + 256 * i] = src[tid + 256 * i];
        if (tid < PCH) tsq[tid] = sq32[(b << 12) + m0 + tid];
    }

    f32x2 qv[32];  // channel c packed {qA[c], qB[c]}
    {
        const float4* qa = (const float4*)(pT + (size_t)n0 * 32);
        const float4* qb = (const float4*)(pT + (size_t)n1 * 32);
#pragma unroll
        for (int c4 = 0; c4 < 8; ++c4) {
            float4 ta = qa[c4], tb = qb[c4];
            qv[4 * c4 + 0] = (f32x2){ta.x, tb.x};
            qv[4 * c4 + 1] = (f32x2){ta.y, tb.y};
            qv[4 * c4 + 2] = (f32x2){ta.z, tb.z};
            qv[4 * c4 + 3] = (f32x2){ta.w, tb.w};
        }
    }
    f32x2 negsq = (f32x2){-sq32[n0], -sq32[n1]};
    unsigned keyA[PK], keyB[PK];
#pragma unroll
    for (int i = 0; i < PK; ++i) { keyA[i] = 0u; keyB[i] = 0u; }

    __syncthreads();

#pragma unroll 2
    for (int mm = 0; mm < PCH; ++mm) {
        const float4* row = (const float4*)(tile + mm * 32);  // wave-uniform broadcast
        f32x2 acc = (f32x2){0.f, 0.f};
#pragma unroll
        for (int c4 = 0; c4 < 8; ++c4) {
            float4 t = row[c4];
            acc = __builtin_elementwise_fma((f32x2){t.x, t.x}, qv[4 * c4 + 0], acc);
            acc = __builtin_elementwise_fma((f32x2){t.y, t.y}, qv[4 * c4 + 1], acc);
            acc = __builtin_elementwise_fma((f32x2){t.z, t.z}, qv[4 * c4 + 2], acc);
            acc = __builtin_elementwise_fma((f32x2){t.w, t.w}, qv[4 * c4 + 3], acc);
        }
        float ts = tsq[mm];
        f32x2 bias = negsq - (f32x2){ts, ts};
        f32x2 d = __builtin_elementwise_fma((f32x2){2.f, 2.f}, acc, bias);
        int mkey = 4095 - (m0 + mm);
        {
            unsigned u = __float_as_uint(d.x);
            unsigned k32 = u ^ (unsigned)(((int)u >> 31) | 0x80000000);
            unsigned cv = (k32 & 0xFFFFF000u) | (unsigned)mkey;
#pragma unroll
            for (int j = 0; j < PK; ++j) {
                unsigned vj = keyA[j];
                unsigned hi = cv > vj ? cv : vj;
                unsigned lo = cv > vj ? vj : cv;
                keyA[j] = hi; cv = lo;
            }
        }
        {
            unsigned u = __float_as_uint(d.y);
            unsigned k32 = u ^ (unsigned)(((int)u >> 31) | 0x80000000);
            unsigned cv = (k32 & 0xFFFFF000u) | (unsigned)mkey;
#pragma unroll
            for (int j = 0; j < PK; ++j) {
                unsigned vj = keyB[j];
                unsigned hi = cv > vj ? cv : vj;
                unsigned lo = cv > vj ? vj : cv;
                keyB[j] = hi; cv = lo;
            }
        }
    }
    size_t base = (size_t)blockIdx.y * PK * (BB * NN);
#pragma unroll
    for (int i = 0; i < PK; ++i) {
        pkey[base + (size_t)i * (BB * NN) + n0] = keyA[i];
        pkey[base + (size_t)i * (BB * NN) + n1] = keyB[i];
    }
}

// ---------------- KNN merge: per (query, group of 8 ranges) -> exact sorted top-16 ----
__global__ __launch_bounds__(256) void knn_merge(const float* __restrict__ pT,
                                                 const double* __restrict__ sq64,
                                                 const unsigned* __restrict__ pkey,
                                                 double* __restrict__ dvals,
                                                 int* __restrict__ didx) {
    int n = blockIdx.x * 256 + threadIdx.x;
    int g = blockIdx.y;
    int b = n >> 12;
    const float* pb = pT + ((size_t)(b << 12)) * 32;
    const double* sqb = sq64 + (b << 12);

    // scan this group's 8 ranges (64 keys) -> top-NK2 keys
    unsigned sk[NK2];
#pragma unroll
    for (int i = 0; i < NK2; ++i) sk[i] = 0u;
    for (int r = g * 8; r < g * 8 + 8; ++r) {
        unsigned kv[PK];
#pragma unroll
        for (int k = 0; k < PK; ++k)
            kv[k] = pkey[(size_t)(r * PK + k) * (BB * NN) + n];  // coalesced batch
        for (int k = 0; k < PK; ++k) {
            unsigned cv = kv[k];
            if (__all(cv <= sk[NK2 - 1])) break;  // lane-keys descend within range
#pragma unroll
            for (int j = 0; j < NK2; ++j) {
                unsigned vj = sk[j];
                unsigned hi = cv > vj ? cv : vj;
                unsigned lo = cv > vj ? vj : cv;
                sk[j] = hi; cv = lo;
            }
        }
    }

    // fp64 exact rerank of the NK2 survivors (chains identical to R2's passing kernel)
    double qv[32];
    const float4* q4 = (const float4*)(pT + (size_t)n * 32);
#pragma unroll
    for (int c4 = 0; c4 < 8; ++c4) {
        float4 t = q4[c4];
        qv[4 * c4] = (double)t.x; qv[4 * c4 + 1] = (double)t.y;
        qv[4 * c4 + 2] = (double)t.z; qv[4 * c4 + 3] = (double)t.w;
    }
    double sqn = 0.0;
#pragma unroll
    for (int c = 0; c < 32; ++c) sqn = fma(qv[c], qv[c], sqn);

    double dv[16];
    int di[16];
#pragma unroll
    for (int i = 0; i < 16; ++i) { dv[i] = -1e300; di[i] = 0x7fffffff; }
#pragma unroll
    for (int u = 0; u < NK2; ++u) {
        int m = 4095 - (int)(sk[u] & 0xFFFu);
        const float4* row = (const float4*)(pb + (size_t)m * 32);
        double dot = 0.0;
#pragma unroll
        for (int c4 = 0; c4 < 8; ++c4) {
            float4 t = row[c4];
            dot = fma((double)t.x, qv[4 * c4], dot);
            dot = fma((double)t.y, qv[4 * c4 + 1], dot);
            dot = fma((double)t.z, qv[4 * c4 + 2], dot);
            dot = fma((double)t.w, qv[4 * c4 + 3], dot);
        }
        double d = 2.0 * dot - sqn - sqb[m];  // self -> exactly 0
        if (d > dv[15] || (d == dv[15] && m < di[15])) {
            double cv = d; int ci = m;
#pragma unroll
            for (int j = 0; j < 16; ++j) {
                bool c = (cv > dv[j]) || (cv == dv[j] && ci < di[j]);
                double nv = c ? cv : dv[j]; double nc = c ? dv[j] : cv;
                int ni = c ? ci : di[j];    int nj = c ? di[j] : ci;
                dv[j] = nv; cv = nc; di[j] = ni; ci = nj;
            }
        }
    }
#pragma unroll
    for (int i = 0; i < 16; ++i) {
        dvals[(size_t)(g * 16 + i) * (BB * NN) + n] = dv[i];
        didx[(size_t)(g * 16 + i) * (BB * NN) + n] = di[i];
    }
}

// ---------------- KNN final: merge 4 sorted exact top-16 lists -> global top-16 --------
__global__ __launch_bounds__(256) void knn_final(const double* __restrict__ dvals,
                                                 const int* __restrict__ didx,
                                                 int* __restrict__ fidx,
                                                 float* __restrict__ fdist) {
    int n = blockIdx.x * 256 + threadIdx.x;
    double dv[16];
    int di[16];
#pragma unroll
    for (int i = 0; i < 16; ++i) { dv[i] = -1e300; di[i] = 0x7fffffff; }
#pragma unroll
    for (int g = 0; g < NG; ++g) {
        double dg[16];
        int ig[16];
#pragma unroll
        for (int j = 0; j < 16; ++j) {
            dg[j] = dvals[(size_t)(g * 16 + j) * (BB * NN) + n];  // coalesced
            ig[j] = didx[(size_t)(g * 16 + j) * (BB * NN) + n];
        }
        for (int j = 0; j < 16; ++j) {
            double cv = dg[j];
            int ci = ig[j];
            bool ins = (cv > dv[15]) || (cv == dv[15] && ci < di[15]);
            if (!__any(ins)) break;  // group lists sorted desc
#pragma unroll
            for (int j2 = 0; j2 < 16; ++j2) {
                bool c = (cv > dv[j2]) || (cv == dv[j2] && ci < di[j2]);
                double nv = c ? cv : dv[j2]; double nc = c ? dv[j2] : cv;
                int ni = c ? ci : di[j2];    int nj = c ? di[j2] : ci;
                dv[j2] = nv; cv = nc; di[j2] = ni; ci = nj;
            }
        }
    }
#pragma unroll
    for (int i = 0; i < 16; ++i) {
        fdist[(size_t)n * 16 + i] = (float)dv[i];
        fidx[(size_t)n * 16 + i] = di[i];
    }
}

// ---------------- Fused pipeline: scalar-uniform weights + batched gathers ----------
__global__ __launch_bounds__(256, 4) void fuse_kernel(
    const float* __restrict__ coords, const float* __restrict__ feat,
    const int* __restrict__ knn_idx, const float* __restrict__ knn_dist,
    const float* __restrict__ W2, const float* __restrict__ W3p,
    const float* __restrict__ W4p, const float* __restrict__ W5,
    const float* __restrict__ g1, const float* __restrict__ b1,
    const float* __restrict__ g2, const float* __restrict__ b2,
    const float* __restrict__ g3, const float* __restrict__ b3,
    const float* __restrict__ g4, const float* __restrict__ b4,
    const float* __restrict__ g5, const float* __restrict__ b5,
    const float* __restrict__ ctrA, const float* __restrict__ nbrB,
    const float* __restrict__ w1d, const int* __restrict__ fidx,
    const float* __restrict__ fdist, float* __restrict__ out) {
    int g = blockIdx.x * 256 + threadIdx.x;
    int k = g & 15;
    int n = (g >> 4) & (NN - 1);
    int b = g >> 16;
    int pn = b * NN + n;

    // coalesced per-(n,k) gathers
    int fnb = fidx[(size_t)pn * 16 + k];
    float fd = fdist[(size_t)pn * 16 + k];
    int cnb = knn_idx[(size_t)pn * 16 + k];
    float kd = knn_dist[(size_t)pn * 16 + k];
    const float4* nB4 = (const float4*)(nbrB + ((size_t)b * NN + fnb) * 64);
    const float4* cA4 = (const float4*)(ctrA + (size_t)pn * 64);
    float cq[3], cn_[3];
#pragma unroll
    for (int j = 0; j < 3; ++j) cq[j] = coords[(size_t)pn * 3 + j];
#pragma unroll
    for (int j = 0; j < 3; ++j) cn_[j] = coords[((size_t)b * NN + cnb) * 3 + j];

    // features_knn (64) = leaky(BN(W1 . edge)) = max(v, 0.2v)
    const f32x2* wd2 = (const f32x2*)w1d;
    const f32x2* g12 = (const f32x2*)g1;
    const f32x2* b12 = (const f32x2*)b1;
    f32x2 fdp = (f32x2){fd, fd};
    f32x2 bni = (f32x2){BN_INV, BN_INV};
    f32x2 pt2 = (f32x2){0.2f, 0.2f};
    f32x2 fkp[32];
#pragma unroll
    for (int half = 0; half < 2; ++half) {
        float4 nbh[8];
#pragma unroll
        for (int i = 0; i < 8; ++i) nbh[i] = nB4[8 * half + i];  // batched gather
#pragma unroll
        for (int j = 0; j < 8; ++j) {
            int o4 = 8 * half + j;
            float4 nb = nbh[j];
            float4 ca = cA4[o4];
            f32x2 s01 = (f32x2){ca.x, ca.y} + (f32x2){nb.x, nb.y};
            f32x2 s23 = (f32x2){ca.z, ca.w} + (f32x2){nb.z, nb.w};
            f32x2 y0 = __builtin_elementwise_fma(wd2[2 * o4 + 0], fdp, s01);
            f32x2 y1 = __builtin_elementwise_fma(wd2[2 * o4 + 1], fdp, s23);
            f32x2 v0 = __builtin_elementwise_fma(g12[2 * o4 + 0] * bni, y0, b12[2 * o4 + 0]);
            f32x2 v1 = __builtin_elementwise_fma(g12[2 * o4 + 1] * bni, y1, b12[2 * o4 + 1]);
            fkp[2 * o4 + 0] = __builtin_elementwise_max(v0, v0 * pt2);
            fkp[2 * o4 + 1] = __builtin_elementwise_max(v1, v1 * pt2);
        }
    }

    // batch-issue feat loads early; used after W3/W4 (hidden under W2/W3 compute)
    float fadd[32];
#pragma unroll
    for (int c = 0; c < 32; ++c) fadd[c] = feat[((size_t)b * 32 + c) * NN + n];

    // features_offset (3) = elu(BN(W2 . fk)); build concat_point pairs
    f32x2 cpp[7];
    float pe[3];
#pragma unroll
    for (int j = 0; j < 3; ++j) {
        const f32x2* w2r = (const f32x2*)(W2 + j * 64);
        f32x2 ap = (f32x2){0.f, 0.f};
#pragma unroll
        for (int i = 0; i < 32; ++i) ap = __builtin_elementwise_fma(w2r[i], fkp[i], ap);
        float a = ap.x + ap.y;
        float t = fmaf(g2[j] * BN_INV, a, b2[j]);
        t = t > 0.f ? t : __expf(t) - 1.f;
        pe[j] = t + cq[j];
    }
    cpp[0] = (f32x2){cq[0], cq[1]};
    cpp[1] = (f32x2){cq[2], cn_[0]};
    cpp[2] = (f32x2){cn_[1], cn_[2]};
    cpp[3] = (f32x2){cq[0] - cn_[0], cq[1] - cn_[1]};
    cpp[4] = (f32x2){cq[2] - cn_[2], kd};
    cpp[5] = (f32x2){pe[0], pe[1]};
    cpp[6] = (f32x2){pe[2], 0.f};

    // point_offset -> features_e ; out_point
    size_t outbase = (((size_t)b * 64) * NN + n) * 16 + k;  // c stride NN*16
    f32x2 fep[16];
#pragma unroll
    for (int c2 = 0; c2 < 16; ++c2) {
        float fv[2];
#pragma unroll
        for (int h = 0; h < 2; ++h) {
            int c = 2 * c2 + h;
            const f32x2* w3r = (const f32x2*)(W3p + c * 14);
            const f32x2* w4r = (const f32x2*)(W4p + c * 14);
            f32x2 a3p = (f32x2){0.f, 0.f}, a4p = (f32x2){0.f, 0.f};
#pragma unroll
            for (int j = 0; j < 7; ++j) {
                a3p = __builtin_elementwise_fma(w3r[j], cpp[j], a3p);
                a4p = __builtin_elementwise_fma(w4r[j], cpp[j], a4p);
            }
            float a3 = a3p.x + a3p.y, a4 = a4p.x + a4p.y;
            float po = fmaf(g3[c] * BN_INV, a3, b3[c]);
            po = po > 0.f ? po : __expf(po) - 1.f;
            fv[h] = po + fadd[c];
            float op = fmaf(g4[c] * BN_INV, a4, b4[c]);
            op = op > 0.f ? op : __expf(op) - 1.f;
            out[outbase + (size_t)c * (NN * 16)] = op;
        }
        fep[c2] = (f32x2){fv[0], fv[1]};
    }

    // out_feature = elu(BN(W5 . [fk(64), fe(32)]))
#pragma unroll
    for (int c = 0; c < 32; ++c) {
        const f32x2* w5r = (const f32x2*)(W5 + c * 96);
        f32x2 ap = (f32x2){0.f, 0.f};
#pragma unroll
        for (int i = 0; i < 32; ++i) ap = __builtin_elementwise_fma(w5r[i], fkp[i], ap);
#pragma unroll
        for (int i = 0; i < 16; ++i) ap = __builtin_elementwise_fma(w5r[32 + i], fep[i], ap);
        float a5 = ap.x + ap.y;
        float v = fmaf(g5[c] * BN_INV, a5, b5[c]);
        v = v > 0.f ? v : __expf(v) - 1.f;
        out[outbase + (size_t)(32 + c) * (NN * 16)] = v;
    }
}

extern "C" void kernel_launch(void* const* d_in, const int* in_sizes, int n_in,
                              void* d_out, int out_size, void* d_ws, size_t ws_size,
                              hipStream_t stream) {
    const float* coords   = (const float*)d_in[0];
    const float* features = (const float*)d_in[1];
    const int*   knn_idx  = (const int*)d_in[2];
    const float* knn_dist = (const float*)d_in[3];
    const float* W1 = (const float*)d_in[4];
    const float* W2 = (const float*)d_in[5];
    const float* W3 = (const float*)d_in[6];
    const float* W4 = (const float*)d_in[7];
    const float* W5 = (const float*)d_in[8];
    const float* g1 = (const float*)d_in[9];
    const float* b1 = (const float*)d_in[10];
    const float* g2 = (const float*)d_in[11];
    const float* b2 = (const float*)d_in[12];
    const float* g3 = (const float*)d_in[13];
    const float* b3 = (const float*)d_in[14];
    const float* g4 = (const float*)d_in[15];
    const float* b4 = (const float*)d_in[16];
    const float* g5 = (const float*)d_in[17];
    const float* b5 = (const float*)d_in[18];
    float* out = (float*)d_out;

    // workspace layout (float slots)
    float*  pT    = (float*)d_ws;                  // 524288
    float*  sq32  = pT + BB * NN * 32;             // 16384
    double* sq64  = (double*)(sq32 + BB * NN);     // 16384 doubles (32768 slots)
    float*  fdist = (float*)(sq64 + BB * NN);      // 262144
    int*    fidx  = (int*)(fdist + BB * NN * 16);  // 262144
    float*  Aw    = (float*)(fidx + BB * NN * 16); // 2048
    float*  Bw    = Aw + 2048;                     // 2048
    float*  w1d   = Bw + 2048;                     // 64
    float*  W3p   = w1d + 64;                      // 448 (pad to 512)
    float*  W4p   = W3p + 512;                     // 448 (pad to 512)
    float*  ctrA  = W4p + 512;                     // B*N*64 = 1048576
    float*  nbrB  = ctrA + BB * NN * 64;           // B*N*64 = 1048576
    // scratch in d_out (67 MB), disjoint lifetimes vs final output write:
    //   pkey  [RS*PK][B*N] u32 = 16 MB   (prefilter -> merge)
    //   dvals [NG*16][B*N] f64 = 8 MB    (merge -> final)
    //   didx  [NG*16][B*N] i32 = 4 MB
    unsigned* pkey  = (unsigned*)d_out;
    double*   dvals = (double*)((char*)d_out + ((size_t)RS * PK * BB * NN * 4));
    int*      didx  = (int*)((char*)dvals + ((size_t)NG * 16 * BB * NN * 8));

    hipLaunchKernelGGL(p0_weights, dim3(1), dim3(256), 0, stream,
                       W1, W3, W4, Aw, Bw, w1d, W3p, W4p);
    hipLaunchKernelGGL(p1_transpose, dim3(BB * NN / 256), dim3(256), 0, stream,
                       features, pT, sq32, sq64);
    hipLaunchKernelGGL(knn_prefilter, dim3(BB * NN / 512, RS), dim3(256), 0, stream,
                       pT, sq32, pkey);
    hipLaunchKernelGGL(knn_merge, dim3(BB * NN / 256, NG), dim3(256), 0, stream,
                       pT, sq64, pkey, dvals, didx);
    hipLaunchKernelGGL(knn_final, dim3(BB * NN / 256), dim3(256), 0, stream,
                       dvals, didx, fidx, fdist);
    hipLaunchKernelGGL(p2_proj, dim3(BB * NN * 64 / 256), dim3(256), 0, stream,
                       pT, Aw, Bw, ctrA, nbrB);
    hipLaunchKernelGGL(fuse_kernel, dim3(BB * NN * KK / 256), dim3(256), 0, stream,
                       coords, features, knn_idx, knn_dist, W2, W3p, W4p, W5,
                       g1, b1, g2, b2, g3, b3, g4, b4, g5, b5,
                       ctrA, nbrB, w1d, fidx, fdist, out);
}

// Round 10
// 310.906 us; speedup vs baseline: 1.1364x; 1.1364x over previous
//
#include <hip/hip_runtime.h>
#include <math.h>

#define BB 4
#define NN 4096
#define KK 16
#define CIN 32
#define BN_INV 0.9999950000375f

#define RS 32    // candidate ranges per query
#define PCH 128  // candidates per range (NN/RS)
#define PK 8     // prefilter top-K per range
#define NG 8     // merge groups (4 ranges each)
#define NK2 20   // keys fp64-reranked per group (of 32)

typedef float f32x2 __attribute__((ext_vector_type(2)));
typedef float f32x4 __attribute__((ext_vector_type(4)));

// ---------------- P0: derived W1 weights + padded W3/W4 copies ----------------
__global__ void p0_weights(const float* __restrict__ W1,
                           const float* __restrict__ W3, const float* __restrict__ W4,
                           float* __restrict__ Aw, float* __restrict__ Bw,
                           float* __restrict__ w1d,
                           float* __restrict__ W3p, float* __restrict__ W4p) {
    int t = threadIdx.x;
    for (int i = t; i < 64 * 32; i += 256) {
        int o = i >> 5, c = i & 31;
        Aw[i] = W1[o * 128 + c] - W1[o * 128 + 64 + c];
        Bw[i] = W1[o * 128 + 32 + c] + W1[o * 128 + 64 + c];
    }
    if (t < 64) {
        float s = 0.f;
        for (int c = 96; c < 128; ++c) s += W1[t * 128 + c];
        w1d[t] = s;
    }
    for (int i = t; i < 32 * 14; i += 256) {
        int r = i / 14, j = i - r * 14;
        W3p[i] = (j < 13) ? W3[r * 13 + j] : 0.f;
        W4p[i] = (j < 13) ? W4[r * 13 + j] : 0.f;
    }
}

// ---------------- P1: transpose features to [B,N,32] + fp32/fp64 norms ----------------
__global__ void p1_transpose(const float* __restrict__ f, float* __restrict__ pT,
                             float* __restrict__ sq32, double* __restrict__ sq64) {
    int g = blockIdx.x * 256 + threadIdx.x;  // b*N + n
    int b = g >> 12, n = g & (NN - 1);
    float v[CIN];
#pragma unroll
    for (int c = 0; c < CIN; ++c) v[c] = f[(b * CIN + c) * NN + n];
#pragma unroll
    for (int c = 0; c < CIN; ++c) pT[(size_t)g * CIN + c] = v[c];
    // sequential chain — BITWISE identical to knn_prefilter's per-lane dot chain
    float s32 = 0.f;
#pragma unroll
    for (int c = 0; c < CIN; ++c) s32 = fmaf(v[c], v[c], s32);
    sq32[g] = s32;
    // sequential fp64 chain — must match knn_merge's rerank chains
    double s64 = 0.0;
#pragma unroll
    for (int c = 0; c < CIN; ++c) s64 = fma((double)v[c], (double)v[c], s64);
    sq64[g] = s64;
}

// ---------------- P2: per-point projections ctrA = A*p, nbrB = B*p ----------------
__global__ __launch_bounds__(256) void p2_proj(const float* __restrict__ pT,
                                               const float* __restrict__ Aw,
                                               const float* __restrict__ Bw,
                                               float* __restrict__ ctrA,
                                               float* __restrict__ nbrB) {
    __shared__ float sA[32 * 64], sB[32 * 64];
    for (int i = threadIdx.x; i < 2048; i += 256) {
        int o = i >> 5, c = i & 31;
        sA[c * 64 + o] = Aw[i];
        sB[c * 64 + o] = Bw[i];
    }
    __syncthreads();
    int g = blockIdx.x * 256 + threadIdx.x;  // (b*N+n)*64 + o
    int o = g & 63;
    int pn = g >> 6;
    const float* p = pT + (size_t)pn * 32;
    float a = 0.f, bb = 0.f;
#pragma unroll
    for (int c = 0; c < 32; ++c) {
        float pv = p[c];
        a = fmaf(sA[c * 64 + o], pv, a);
        bb = fmaf(sB[c * 64 + o], pv, bb);
    }
    ctrA[g] = a;
    nbrB[g] = bb;
}

#define KINS(KARR, DVAL)                                                  \
    {                                                                     \
        unsigned u_ = __float_as_uint(DVAL);                              \
        unsigned k32_ = u_ ^ (unsigned)(((int)u_ >> 31) | 0x80000000);    \
        unsigned cv_ = (k32_ & 0xFFFFF000u) | (unsigned)mkey;             \
        _Pragma("unroll")                                                 \
        for (int j_ = 0; j_ < PK; ++j_) {                                 \
            unsigned vj_ = KARR[j_];                                      \
            unsigned hi_ = cv_ > vj_ ? cv_ : vj_;                         \
            unsigned lo_ = cv_ > vj_ ? vj_ : cv_;                         \
            KARR[j_] = hi_; cv_ = lo_;                                    \
        }                                                                 \
    }

// ---------------- KNN prefilter: 4 queries/thread packed in pk lanes ----------------
__global__ __launch_bounds__(256) void knn_prefilter(const float* __restrict__ pT,
                                                     const float* __restrict__ sq32,
                                                     unsigned* __restrict__ pkey) {
    __shared__ float tile[PCH * 32];   // 16 KB candidate tile
    __shared__ float tsq[PCH];
    int tid = threadIdx.x;
    int qbase = blockIdx.x * 1024;
    int n0 = qbase + tid;              // queries n0, n0+256, n0+512, n0+768
    int b = n0 >> 12;
    const float* pb = pT + ((size_t)(b << 12)) * 32;
    int m0 = blockIdx.y * PCH;

    {
        const float4* src = (const float4*)(pb + (size_t)m0 * 32);
        float4* dst = (float4*)tile;
#pragma unroll
        for (int i = 0; i < 4; ++i) dst[tid + 256 * i] = src[tid + 256 * i];
        if (tid < PCH) tsq[tid] = sq32[(b << 12) + m0 + tid];
    }

    f32x4 qv[32];  // channel c packed {q0[c], q1[c], q2[c], q3[c]}
    {
        const float4* qa = (const float4*)(pT + (size_t)n0 * 32);
        const float4* qb = (const float4*)(pT + (size_t)(n0 + 256) * 32);
        const float4* qc = (const float4*)(pT + (size_t)(n0 + 512) * 32);
        const float4* qd = (const float4*)(pT + (size_t)(n0 + 768) * 32);
#pragma unroll
        for (int c4 = 0; c4 < 8; ++c4) {
            float4 ta = qa[c4], tb = qb[c4], tc = qc[c4], td = qd[c4];
            qv[4 * c4 + 0] = (f32x4){ta.x, tb.x, tc.x, td.x};
            qv[4 * c4 + 1] = (f32x4){ta.y, tb.y, tc.y, td.y};
            qv[4 * c4 + 2] = (f32x4){ta.z, tb.z, tc.z, td.z};
            qv[4 * c4 + 3] = (f32x4){ta.w, tb.w, tc.w, td.w};
        }
    }
    f32x4 negsq = (f32x4){-sq32[n0], -sq32[n0 + 256], -sq32[n0 + 512], -sq32[n0 + 768]};
    unsigned key0[PK], key1[PK], key2[PK], key3[PK];
#pragma unroll
    for (int i = 0; i < PK; ++i) { key0[i] = 0u; key1[i] = 0u; key2[i] = 0u; key3[i] = 0u; }

    __syncthreads();

#pragma unroll 2
    for (int mm = 0; mm < PCH; ++mm) {
        const float4* row = (const float4*)(tile + mm * 32);  // wave-uniform broadcast
        f32x4 acc = (f32x4){0.f, 0.f, 0.f, 0.f};
#pragma unroll
        for (int c4 = 0; c4 < 8; ++c4) {
            float4 t = row[c4];
            acc = __builtin_elementwise_fma((f32x4){t.x, t.x, t.x, t.x}, qv[4 * c4 + 0], acc);
            acc = __builtin_elementwise_fma((f32x4){t.y, t.y, t.y, t.y}, qv[4 * c4 + 1], acc);
            acc = __builtin_elementwise_fma((f32x4){t.z, t.z, t.z, t.z}, qv[4 * c4 + 2], acc);
            acc = __builtin_elementwise_fma((f32x4){t.w, t.w, t.w, t.w}, qv[4 * c4 + 3], acc);
        }
        float ts = tsq[mm];
        f32x4 d = __builtin_elementwise_fma((f32x4){2.f, 2.f, 2.f, 2.f}, acc,
                                            negsq - (f32x4){ts, ts, ts, ts});
        int mkey = 4095 - (m0 + mm);
        KINS(key0, d.x)
        KINS(key1, d.y)
        KINS(key2, d.z)
        KINS(key3, d.w)
    }
    size_t base = (size_t)blockIdx.y * PK * (BB * NN);
#pragma unroll
    for (int i = 0; i < PK; ++i) {
        pkey[base + (size_t)i * (BB * NN) + n0] = key0[i];
        pkey[base + (size_t)i * (BB * NN) + n0 + 256] = key1[i];
        pkey[base + (size_t)i * (BB * NN) + n0 + 512] = key2[i];
        pkey[base + (size_t)i * (BB * NN) + n0 + 768] = key3[i];
    }
}

// ---------------- KNN merge: per (query, group of 4 ranges) -> exact sorted top-16 ----
__global__ __launch_bounds__(256) void knn_merge(const float* __restrict__ pT,
                                                 const double* __restrict__ sq64,
                                                 const unsigned* __restrict__ pkey,
                                                 double* __restrict__ dvals,
                                                 int* __restrict__ didx) {
    int n = blockIdx.x * 256 + threadIdx.x;
    int g = blockIdx.y;
    int b = n >> 12;
    const float* pb = pT + ((size_t)(b << 12)) * 32;
    const double* sqb = sq64 + (b << 12);

    // scan this group's 4 ranges (32 keys) -> top-NK2 keys
    unsigned sk[NK2];
#pragma unroll
    for (int i = 0; i < NK2; ++i) sk[i] = 0u;
#pragma unroll 1
    for (int r = g * 4; r < g * 4 + 4; ++r) {
        unsigned kv[PK];
#pragma unroll
        for (int k = 0; k < PK; ++k)
            kv[k] = pkey[(size_t)(r * PK + k) * (BB * NN) + n];  // coalesced batch
        for (int k = 0; k < PK; ++k) {
            unsigned cv = kv[k];
            if (__all(cv <= sk[NK2 - 1])) break;  // lane-keys descend within range
#pragma unroll
            for (int j = 0; j < NK2; ++j) {
                unsigned vj = sk[j];
                unsigned hi = cv > vj ? cv : vj;
                unsigned lo = cv > vj ? vj : cv;
                sk[j] = hi; cv = lo;
            }
        }
    }

    // fp64 exact rerank of the NK2 survivors (chains identical to R2's passing kernel)
    double qv[32];
    const float4* q4 = (const float4*)(pT + (size_t)n * 32);
#pragma unroll
    for (int c4 = 0; c4 < 8; ++c4) {
        float4 t = q4[c4];
        qv[4 * c4] = (double)t.x; qv[4 * c4 + 1] = (double)t.y;
        qv[4 * c4 + 2] = (double)t.z; qv[4 * c4 + 3] = (double)t.w;
    }
    double sqn = 0.0;
#pragma unroll
    for (int c = 0; c < 32; ++c) sqn = fma(qv[c], qv[c], sqn);

    double dv[16];
    int di[16];
#pragma unroll
    for (int i = 0; i < 16; ++i) { dv[i] = -1e300; di[i] = 0x7fffffff; }
#pragma unroll 2
    for (int u = 0; u < NK2; ++u) {
        int m = 4095 - (int)(sk[u] & 0xFFFu);
        const float4* row = (const float4*)(pb + (size_t)m * 32);
        double dot = 0.0;
#pragma unroll
        for (int c4 = 0; c4 < 8; ++c4) {
            float4 t = row[c4];
            dot = fma((double)t.x, qv[4 * c4], dot);
            dot = fma((double)t.y, qv[4 * c4 + 1], dot);
            dot = fma((double)t.z, qv[4 * c4 + 2], dot);
            dot = fma((double)t.w, qv[4 * c4 + 3], dot);
        }
        double d = 2.0 * dot - sqn - sqb[m];  // self -> exactly 0
        if (d > dv[15] || (d == dv[15] && m < di[15])) {
            double cv = d; int ci = m;
#pragma unroll
            for (int j = 0; j < 16; ++j) {
                bool c = (cv > dv[j]) || (cv == dv[j] && ci < di[j]);
                double nv = c ? cv : dv[j]; double nc = c ? dv[j] : cv;
                int ni = c ? ci : di[j];    int nj = c ? di[j] : ci;
                dv[j] = nv; cv = nc; di[j] = ni; ci = nj;
            }
        }
    }
#pragma unroll
    for (int i = 0; i < 16; ++i) {
        dvals[(size_t)(g * 16 + i) * (BB * NN) + n] = dv[i];
        didx[(size_t)(g * 16 + i) * (BB * NN) + n] = di[i];
    }
}

// ---------------- KNN final: merge NG sorted exact top-16 lists -> global top-16 -------
__global__ __launch_bounds__(256) void knn_final(const double* __restrict__ dvals,
                                                 const int* __restrict__ didx,
                                                 int* __restrict__ fidx,
                                                 float* __restrict__ fdist) {
    int n = blockIdx.x * 256 + threadIdx.x;
    double dv[16];
    int di[16];
#pragma unroll
    for (int i = 0; i < 16; ++i) { dv[i] = -1e300; di[i] = 0x7fffffff; }
#pragma unroll 1
    for (int g = 0; g < NG; ++g) {
        double dg[16];
        int ig[16];
#pragma unroll
        for (int j = 0; j < 16; ++j) {
            dg[j] = dvals[(size_t)(g * 16 + j) * (BB * NN) + n];  // coalesced
            ig[j] = didx[(size_t)(g * 16 + j) * (BB * NN) + n];
        }
        for (int j = 0; j < 16; ++j) {
            double cv = dg[j];
            int ci = ig[j];
            bool ins = (cv > dv[15]) || (cv == dv[15] && ci < di[15]);
            if (!__any(ins)) break;  // group lists sorted desc
#pragma unroll
            for (int j2 = 0; j2 < 16; ++j2) {
                bool c = (cv > dv[j2]) || (cv == dv[j2] && ci < di[j2]);
                double nv = c ? cv : dv[j2]; double nc = c ? dv[j2] : cv;
                int ni = c ? ci : di[j2];    int nj = c ? di[j2] : ci;
                dv[j2] = nv; cv = nc; di[j2] = ni; ci = nj;
            }
        }
    }
#pragma unroll
    for (int i = 0; i < 16; ++i) {
        fdist[(size_t)n * 16 + i] = (float)dv[i];
        fidx[(size_t)n * 16 + i] = di[i];
    }
}

// ---------------- Fused pipeline: scalar-uniform weights, rolled W5 loop ----------
__global__ __launch_bounds__(256, 4) void fuse_kernel(
    const float* __restrict__ coords, const float* __restrict__ feat,
    const int* __restrict__ knn_idx, const float* __restrict__ knn_dist,
    const float* __restrict__ W2, const float* __restrict__ W3p,
    const float* __restrict__ W4p, const float* __restrict__ W5,
    const float* __restrict__ g1, const float* __restrict__ b1,
    const float* __restrict__ g2, const float* __restrict__ b2,
    const float* __restrict__ g3, const float* __restrict__ b3,
    const float* __restrict__ g4, const float* __restrict__ b4,
    const float* __restrict__ g5, const float* __restrict__ b5,
    const float* __restrict__ ctrA, const float* __restrict__ nbrB,
    const float* __restrict__ w1d, const int* __restrict__ fidx,
    const float* __restrict__ fdist, float* __restrict__ out) {
    int g = blockIdx.x * 256 + threadIdx.x;
    int k = g & 15;
    int n = (g >> 4) & (NN - 1);
    int b = g >> 16;
    int pn = b * NN + n;

    // coalesced per-(n,k) gathers
    int fnb = fidx[(size_t)pn * 16 + k];
    float fd = fdist[(size_t)pn * 16 + k];
    int cnb = knn_idx[(size_t)pn * 16 + k];
    float kd = knn_dist[(size_t)pn * 16 + k];
    const float4* nB4 = (const float4*)(nbrB + ((size_t)b * NN + fnb) * 64);
    const float4* cA4 = (const float4*)(ctrA + (size_t)pn * 64);
    float cq[3], cn_[3];
#pragma unroll
    for (int j = 0; j < 3; ++j) cq[j] = coords[(size_t)pn * 3 + j];
#pragma unroll
    for (int j = 0; j < 3; ++j) cn_[j] = coords[((size_t)b * NN + cnb) * 3 + j];

    // features_knn (64) = leaky(BN(W1 . edge)) = max(v, 0.2v)
    const f32x2* wd2 = (const f32x2*)w1d;
    const f32x2* g12 = (const f32x2*)g1;
    const f32x2* b12 = (const f32x2*)b1;
    f32x2 fdp = (f32x2){fd, fd};
    f32x2 bni = (f32x2){BN_INV, BN_INV};
    f32x2 pt2 = (f32x2){0.2f, 0.2f};
    f32x2 fkp[32];
#pragma unroll
    for (int half = 0; half < 2; ++half) {
        float4 nbh[8];
#pragma unroll
        for (int i = 0; i < 8; ++i) nbh[i] = nB4[8 * half + i];  // batched gather
#pragma unroll
        for (int j = 0; j < 8; ++j) {
            int o4 = 8 * half + j;
            float4 nb = nbh[j];
            float4 ca = cA4[o4];
            f32x2 s01 = (f32x2){ca.x, ca.y} + (f32x2){nb.x, nb.y};
            f32x2 s23 = (f32x2){ca.z, ca.w} + (f32x2){nb.z, nb.w};
            f32x2 y0 = __builtin_elementwise_fma(wd2[2 * o4 + 0], fdp, s01);
            f32x2 y1 = __builtin_elementwise_fma(wd2[2 * o4 + 1], fdp, s23);
            f32x2 v0 = __builtin_elementwise_fma(g12[2 * o4 + 0] * bni, y0, b12[2 * o4 + 0]);
            f32x2 v1 = __builtin_elementwise_fma(g12[2 * o4 + 1] * bni, y1, b12[2 * o4 + 1]);
            fkp[2 * o4 + 0] = __builtin_elementwise_max(v0, v0 * pt2);
            fkp[2 * o4 + 1] = __builtin_elementwise_max(v1, v1 * pt2);
        }
    }

    // batch-issue feat loads early
    float fadd[32];
#pragma unroll
    for (int c = 0; c < 32; ++c) fadd[c] = feat[((size_t)b * 32 + c) * NN + n];

    // features_offset (3) = elu(BN(W2 . fk)); build concat_point pairs
    f32x2 cpp[7];
    float pe[3];
#pragma unroll
    for (int j = 0; j < 3; ++j) {
        const f32x2* w2r = (const f32x2*)(W2 + j * 64);
        f32x2 ap = (f32x2){0.f, 0.f};
#pragma unroll
        for (int i = 0; i < 32; ++i) ap = __builtin_elementwise_fma(w2r[i], fkp[i], ap);
        float a = ap.x + ap.y;
        float t = fmaf(g2[j] * BN_INV, a, b2[j]);
        t = t > 0.f ? t : __expf(t) - 1.f;
        pe[j] = t + cq[j];
    }
    cpp[0] = (f32x2){cq[0], cq[1]};
    cpp[1] = (f32x2){cq[2], cn_[0]};
    cpp[2] = (f32x2){cn_[1], cn_[2]};
    cpp[3] = (f32x2){cq[0] - cn_[0], cq[1] - cn_[1]};
    cpp[4] = (f32x2){cq[2] - cn_[2], kd};
    cpp[5] = (f32x2){pe[0], pe[1]};
    cpp[6] = (f32x2){pe[2], 0.f};

    // point_offset -> features_e ; out_point (unrolled: fep writes must be static)
    size_t outbase = (((size_t)b * 64) * NN + n) * 16 + k;  // c stride NN*16
    f32x2 fep[16];
#pragma unroll
    for (int c2 = 0; c2 < 16; ++c2) {
        float fv[2];
#pragma unroll
        for (int h = 0; h < 2; ++h) {
            int c = 2 * c2 + h;
            const f32x2* w3r = (const f32x2*)(W3p + c * 14);
            const f32x2* w4r = (const f32x2*)(W4p + c * 14);
            f32x2 a3p = (f32x2){0.f, 0.f}, a4p = (f32x2){0.f, 0.f};
#pragma unroll
            for (int j = 0; j < 7; ++j) {
                a3p = __builtin_elementwise_fma(w3r[j], cpp[j], a3p);
                a4p = __builtin_elementwise_fma(w4r[j], cpp[j], a4p);
            }
            float a3 = a3p.x + a3p.y, a4 = a4p.x + a4p.y;
            float po = fmaf(g3[c] * BN_INV, a3, b3[c]);
            po = po > 0.f ? po : __expf(po) - 1.f;
            fv[h] = po + fadd[c];
            float op = fmaf(g4[c] * BN_INV, a4, b4[c]);
            op = op > 0.f ? op : __expf(op) - 1.f;
            out[outbase + (size_t)c * (NN * 16)] = op;
        }
        fep[c2] = (f32x2){fv[0], fv[1]};
    }

    // out_feature = elu(BN(W5 . [fk(64), fe(32)])) — ROLLED loop to shrink I-footprint
#pragma unroll 1
    for (int c = 0; c < 32; ++c) {
        const f32x2* w5r = (const f32x2*)(W5 + c * 96);
        f32x2 ap = (f32x2){0.f, 0.f};
#pragma unroll
        for (int i = 0; i < 32; ++i) ap = __builtin_elementwise_fma(w5r[i], fkp[i], ap);
#pragma unroll
        for (int i = 0; i < 16; ++i) ap = __builtin_elementwise_fma(w5r[32 + i], fep[i], ap);
        float a5 = ap.x + ap.y;
        float v = fmaf(g5[c] * BN_INV, a5, b5[c]);
        v = v > 0.f ? v : __expf(v) - 1.f;
        out[outbase + (size_t)(32 + c) * (NN * 16)] = v;
    }
}

extern "C" void kernel_launch(void* const* d_in, const int* in_sizes, int n_in,
                              void* d_out, int out_size, void* d_ws, size_t ws_size,
                              hipStream_t stream) {
    const float* coords   = (const float*)d_in[0];
    const float* features = (const float*)d_in[1];
    const int*   knn_idx  = (const int*)d_in[2];
    const float* knn_dist = (const float*)d_in[3];
    const float* W1 = (const float*)d_in[4];
    const float* W2 = (const float*)d_in[5];
    const float* W3 = (const float*)d_in[6];
    const float* W4 = (const float*)d_in[7];
    const float* W5 = (const float*)d_in[8];
    const float* g1 = (const float*)d_in[9];
    const float* b1 = (const float*)d_in[10];
    const float* g2 = (const float*)d_in[11];
    const float* b2 = (const float*)d_in[12];
    const float* g3 = (const float*)d_in[13];
    const float* b3 = (const float*)d_in[14];
    const float* g4 = (const float*)d_in[15];
    const float* b4 = (const float*)d_in[16];
    const float* g5 = (const float*)d_in[17];
    const float* b5 = (const float*)d_in[18];
    float* out = (float*)d_out;

    // workspace layout (float slots)
    float*  pT    = (float*)d_ws;                  // 524288
    float*  sq32  = pT + BB * NN * 32;             // 16384
    double* sq64  = (double*)(sq32 + BB * NN);     // 16384 doubles (32768 slots)
    float*  fdist = (float*)(sq64 + BB * NN);      // 262144
    int*    fidx  = (int*)(fdist + BB * NN * 16);  // 262144
    float*  Aw    = (float*)(fidx + BB * NN * 16); // 2048
    float*  Bw    = Aw + 2048;                     // 2048
    float*  w1d   = Bw + 2048;                     // 64
    float*  W3p   = w1d + 64;                      // 448 (pad to 512)
    float*  W4p   = W3p + 512;                     // 448 (pad to 512)
    float*  ctrA  = W4p + 512;                     // B*N*64 = 1048576
    float*  nbrB  = ctrA + BB * NN * 64;           // B*N*64 = 1048576
    // scratch in d_out (67 MB), disjoint lifetimes vs final output write:
    //   pkey  [RS*PK][B*N] u32 = 16.8 MB   (prefilter -> merge)
    //   dvals [NG*16][B*N] f64 = 16.8 MB   (merge -> final)
    //   didx  [NG*16][B*N] i32 = 8.4 MB
    unsigned* pkey  = (unsigned*)d_out;
    double*   dvals = (double*)((char*)d_out + ((size_t)RS * PK * BB * NN * 4));
    int*      didx  = (int*)((char*)dvals + ((size_t)NG * 16 * BB * NN * 8));

    hipLaunchKernelGGL(p0_weights, dim3(1), dim3(256), 0, stream,
                       W1, W3, W4, Aw, Bw, w1d, W3p, W4p);
    hipLaunchKernelGGL(p1_transpose, dim3(BB * NN / 256), dim3(256), 0, stream,
                       features, pT, sq32, sq64);
    hipLaunchKernelGGL(knn_prefilter, dim3(BB * NN / 1024, RS), dim3(256), 0, stream,
                       pT, sq32, pkey);
    hipLaunchKernelGGL(knn_merge, dim3(BB * NN / 256, NG), dim3(256), 0, stream,
                       pT, sq64, pkey, dvals, didx);
    hipLaunchKernelGGL(knn_final, dim3(BB * NN / 256), dim3(256), 0, stream,
                       dvals, didx, fidx, fdist);
    hipLaunchKernelGGL(p2_proj, dim3(BB * NN * 64 / 256), dim3(256), 0, stream,
                       pT, Aw, Bw, ctrA, nbrB);
    hipLaunchKernelGGL(fuse_kernel, dim3(BB * NN * KK / 256), dim3(256), 0, stream,
                       coords, features, knn_idx, knn_dist, W2, W3p, W4p, W5,
                       g1, b1, g2, b2, g3, b3, g4, b4, g5, b5,
                       ctrA, nbrB, w1d, fidx, fdist, out);
}